// Round 5
// baseline (281.500 us; speedup 1.0000x reference)
//
#include <hip/hip_runtime.h>

// GCN layer: out = sum_r segment_sum(vals_r * inp[src_r], dst_r) @ W_r
// Round 5 (aggregate-first):
//   1) inp -> bf16 (12.8 MB), W -> Wt[r][n][k] bf16.
//   2) compact CSR keyed by seg=(r*N+dst): hist -> 3-kernel scan -> fill
//      (6.4 MB contiguous edge records; no sparse bucket line-thrash).
//   3) gather_agg: agg[seg] = sum val * inp_bf16[src]  (random reads hit
//      12.8 MB L2-resident table; agg bf16, 102 MB streamed write).
//   4) mfma_gemm: out[n] = sum_r agg[r][n] @ W_r, all relations accumulated
//      in registers, out written f32 once. No h intermediate.
// N=50000, R=8, E=100000, IN=OUT=128.

constexpr int IN  = 128;
constexpr int OUT = 128;
constexpr int LDK = 136;   // padded LDS row (bf16 elems) = 272 B

typedef __attribute__((ext_vector_type(8))) short bf16x8;
typedef __attribute__((ext_vector_type(4))) float f32x4;

__device__ inline unsigned short f2bf(float f) {
    unsigned int u = __float_as_uint(f);
    u += 0x7fffu + ((u >> 16) & 1u);          // RNE
    return (unsigned short)(u >> 16);
}
__device__ inline float bflo(unsigned int u) { return __uint_as_float(u << 16); }
__device__ inline float bfhi(unsigned int u) { return __uint_as_float(u & 0xffff0000u); }

// ---------------- converts --------------------------------------------------
__global__ __launch_bounds__(256) void conv_inp_kernel(
    const float* __restrict__ x, unsigned short* __restrict__ y, int n8)
{
    const int i = blockIdx.x * 256 + threadIdx.x;
    if (i >= n8) return;
    const float4 a = ((const float4*)x)[i * 2];
    const float4 b = ((const float4*)x)[i * 2 + 1];
    uint4 o;
    o.x = (unsigned)f2bf(a.x) | ((unsigned)f2bf(a.y) << 16);
    o.y = (unsigned)f2bf(a.z) | ((unsigned)f2bf(a.w) << 16);
    o.z = (unsigned)f2bf(b.x) | ((unsigned)f2bf(b.y) << 16);
    o.w = (unsigned)f2bf(b.z) | ((unsigned)f2bf(b.w) << 16);
    ((uint4*)y)[i] = o;
}

// Wt[r][n][k] = W[r][k][n], bf16
__global__ __launch_bounds__(256) void conv_w_kernel(
    const float* __restrict__ w, unsigned short* __restrict__ wt, int total)
{
    const int t = blockIdx.x * 256 + threadIdx.x;
    if (t >= total) return;
    const int r = t >> 14, rem = t & 16383;
    const int n = rem >> 7, k = rem & 127;
    wt[t] = f2bf(w[(r << 14) + (k << 7) + n]);
}

// ---------------- CSR build: hist + hierarchical scan + fill ----------------
__global__ __launch_bounds__(256) void hist_kernel(
    const int* __restrict__ dst, int* __restrict__ counts,
    int n_edges, int n_nodes)
{
    const int e = blockIdx.x * 256 + threadIdx.x;
    if (e >= n_edges) return;
    const size_t g = (size_t)blockIdx.y * n_edges + e;
    atomicAdd(&counts[blockIdx.y * n_nodes + dst[g]], 1);
}

// block handles 1024 counts (4/thread): local exclusive offs + blocksum[b]
__global__ __launch_bounds__(256) void scan_local_kernel(
    const int* __restrict__ counts, int* __restrict__ offs,
    int* __restrict__ blocksum, int S)
{
    __shared__ int ps[256];
    const int tid = threadIdx.x;
    const int base = blockIdx.x * 1024 + tid * 4;
    int c[4];
    #pragma unroll
    for (int i = 0; i < 4; ++i) c[i] = (base + i < S) ? counts[base + i] : 0;
    const int total = c[0] + c[1] + c[2] + c[3];
    ps[tid] = total;
    __syncthreads();
    #pragma unroll
    for (int d = 1; d < 256; d <<= 1) {
        const int v = (tid >= d) ? ps[tid - d] : 0;
        __syncthreads();
        ps[tid] += v;
        __syncthreads();
    }
    int run = ps[tid] - total;   // exclusive prefix of this thread's quad
    #pragma unroll
    for (int i = 0; i < 4; ++i) {
        if (base + i < S) offs[base + i] = run;
        run += c[i];
    }
    if (tid == 255) blocksum[blockIdx.x] = ps[255];
}

// single block: exclusive-scan blocksum in place; offs[S] = grand total
__global__ __launch_bounds__(256) void scan_top_kernel(
    int* __restrict__ blocksum, int nb, int* __restrict__ offs, int S)
{
    __shared__ int ps[256];
    const int tid = threadIdx.x;
    const int chunk = (nb + 255) / 256;      // <= 8 for S <= 2M
    const int lo = tid * chunk;
    const int hi = (lo + chunk < nb) ? lo + chunk : nb;
    int vals[8];
    int s = 0;
    for (int i = lo; i < hi; ++i) { vals[i - lo] = blocksum[i]; s += vals[i - lo]; }
    ps[tid] = s;
    __syncthreads();
    #pragma unroll
    for (int d = 1; d < 256; d <<= 1) {
        const int v = (tid >= d) ? ps[tid - d] : 0;
        __syncthreads();
        ps[tid] += v;
        __syncthreads();
    }
    int run = ps[tid] - s;
    for (int i = lo; i < hi; ++i) { const int v = vals[i - lo]; blocksum[i] = run; run += v; }
    if (tid == 255) offs[S] = ps[255];
}

__global__ __launch_bounds__(256) void scan_apply_kernel(
    int* __restrict__ offs, const int* __restrict__ blocksum,
    int* __restrict__ cursor, int S)
{
    const int i = blockIdx.x * 256 + threadIdx.x;
    if (i >= S) return;
    const int v = offs[i] + blocksum[i >> 10];
    offs[i] = v;
    cursor[i] = v;
}

__global__ __launch_bounds__(256) void fill_kernel(
    const int* __restrict__ src, const int* __restrict__ dst,
    const float* __restrict__ vals, int* __restrict__ cursor,
    int2* __restrict__ csr, int n_edges, int n_nodes)
{
    const int e = blockIdx.x * 256 + threadIdx.x;
    if (e >= n_edges) return;
    const size_t g = (size_t)blockIdx.y * n_edges + e;
    const int seg = blockIdx.y * n_nodes + dst[g];
    const int pos = atomicAdd(&cursor[seg], 1);
    csr[pos] = make_int2(src[g], __float_as_int(vals[g]));
}

// ---------------- gather_agg: agg[seg] = sum val * inp_bf16[src] ------------
__global__ __launch_bounds__(256) void gather_agg_kernel(
    const unsigned short* __restrict__ inpb, const int2* __restrict__ csr,
    const int* __restrict__ offs, unsigned short* __restrict__ agg, int S)
{
    const int seg = blockIdx.x * 8 + (threadIdx.x >> 5);
    const int lane = threadIdx.x & 31;
    if (seg >= S) return;
    const int b = offs[seg], e = offs[seg + 1];

    float4 acc = make_float4(0.f, 0.f, 0.f, 0.f);
    int j = b;
    for (; j + 4 <= e; j += 4) {
        const int2 r0 = csr[j], r1 = csr[j + 1], r2 = csr[j + 2], r3 = csr[j + 3];
        const uint2 h0 = ((const uint2*)(inpb + (size_t)r0.x * IN))[lane];
        const uint2 h1 = ((const uint2*)(inpb + (size_t)r1.x * IN))[lane];
        const uint2 h2 = ((const uint2*)(inpb + (size_t)r2.x * IN))[lane];
        const uint2 h3 = ((const uint2*)(inpb + (size_t)r3.x * IN))[lane];
        const float v0 = __int_as_float(r0.y), v1 = __int_as_float(r1.y);
        const float v2 = __int_as_float(r2.y), v3 = __int_as_float(r3.y);
        acc.x += v0*bflo(h0.x) + v1*bflo(h1.x) + v2*bflo(h2.x) + v3*bflo(h3.x);
        acc.y += v0*bfhi(h0.x) + v1*bfhi(h1.x) + v2*bfhi(h2.x) + v3*bfhi(h3.x);
        acc.z += v0*bflo(h0.y) + v1*bflo(h1.y) + v2*bflo(h2.y) + v3*bflo(h3.y);
        acc.w += v0*bfhi(h0.y) + v1*bfhi(h1.y) + v2*bfhi(h2.y) + v3*bfhi(h3.y);
    }
    for (; j < e; ++j) {
        const int2 r0 = csr[j];
        const float v = __int_as_float(r0.y);
        const uint2 hv = ((const uint2*)(inpb + (size_t)r0.x * IN))[lane];
        acc.x += v * bflo(hv.x); acc.y += v * bfhi(hv.x);
        acc.z += v * bflo(hv.y); acc.w += v * bfhi(hv.y);
    }
    uint2 o;
    o.x = (unsigned)f2bf(acc.x) | ((unsigned)f2bf(acc.y) << 16);
    o.y = (unsigned)f2bf(acc.z) | ((unsigned)f2bf(acc.w) << 16);
    ((uint2*)(agg + (size_t)seg * IN))[lane] = o;
}

// ---------------- MFMA GEMM: out = sum_r agg[r] @ W[rel_base+r], f32 out ----
__global__ __launch_bounds__(256) void mfma_gemm(
    const unsigned short* __restrict__ agg,
    const unsigned short* __restrict__ wt,
    float* __restrict__ out, int rel_base, int rel_count,
    int n_nodes, int accum)
{
    __shared__ unsigned short As[128 * LDK];   // 34 KB

    const int row0 = blockIdx.x * 128;
    const int tid = threadIdx.x;
    const int wave = tid >> 6, lane = tid & 63;
    const int m = lane & 15, q = lane >> 4;

    f32x4 acc[8][2];
    #pragma unroll
    for (int mt = 0; mt < 8; ++mt)
        #pragma unroll
        for (int nt = 0; nt < 2; ++nt)
            acc[mt][nt] = (f32x4){0.f, 0.f, 0.f, 0.f};

    for (int r = 0; r < rel_count; ++r) {
        __syncthreads();   // protect As from previous iteration's readers
        {   // stage agg tile for relation r: thread t -> row t/2, half (t&1)
            const int rowl = tid >> 1;
            const int half = (tid & 1) * 64;
            const int grow = row0 + rowl;
            const uint4* gp = (const uint4*)(
                agg + ((size_t)r * n_nodes + grow) * IN + half);
            uint4* lp = (uint4*)&As[rowl * LDK + half];
            #pragma unroll
            for (int i = 0; i < 8; ++i) {
                uint4 v = make_uint4(0u, 0u, 0u, 0u);
                if (grow < n_nodes) v = gp[i];
                lp[i] = v;
            }
        }
        // B fragments for relation r (L2-hot wt table)
        bf16x8 bfrag[2][4];
        {
            const unsigned short* wtr =
                wt + ((size_t)(rel_base + r) * OUT + wave * 32) * IN;
            #pragma unroll
            for (int nt = 0; nt < 2; ++nt)
                #pragma unroll
                for (int ks = 0; ks < 4; ++ks)
                    bfrag[nt][ks] = *(const bf16x8*)(
                        wtr + (size_t)(nt * 16 + m) * IN + ks * 32 + q * 8);
        }
        __syncthreads();

        #pragma unroll
        for (int ks = 0; ks < 4; ++ks) {
            bf16x8 a[8];
            #pragma unroll
            for (int mt = 0; mt < 8; ++mt)
                a[mt] = *(const bf16x8*)&As[(mt * 16 + m) * LDK + ks * 32 + q * 8];
            #pragma unroll
            for (int mt = 0; mt < 8; ++mt) {
                acc[mt][0] = __builtin_amdgcn_mfma_f32_16x16x32_bf16(
                    a[mt], bfrag[0][ks], acc[mt][0], 0, 0, 0);
                acc[mt][1] = __builtin_amdgcn_mfma_f32_16x16x32_bf16(
                    a[mt], bfrag[1][ks], acc[mt][1], 0, 0, 0);
            }
        }
    }

    // C/D: lane holds rows q*4+0..3, col = nt*16 + m
    #pragma unroll
    for (int mt = 0; mt < 8; ++mt) {
        #pragma unroll
        for (int rg = 0; rg < 4; ++rg) {
            const int row = row0 + mt * 16 + q * 4 + rg;
            if (row < n_nodes) {
                float* op = out + (size_t)row * OUT + wave * 32 + m;
                float v0 = acc[mt][0][rg], v1 = acc[mt][1][rg];
                if (accum) { v0 += op[0]; v1 += op[16]; }
                op[0] = v0; op[16] = v1;
            }
        }
    }
}

// ---------------- last resort: per-edge GEMV scatter (no workspace) ---------
__global__ __launch_bounds__(256) void gemv_scatter_kernel(
    const float* __restrict__ inp, const float* __restrict__ weights,
    const int* __restrict__ src, const int* __restrict__ dst,
    const float* __restrict__ vals, float* __restrict__ out, int n_edges)
{
    const int e = blockIdx.x * 4 + (threadIdx.x >> 6);
    if (e >= n_edges) return;
    const int lane = threadIdx.x & 63;
    const int r = blockIdx.y;
    const size_t g = (size_t)r * n_edges + e;
    const int s = src[g], d = dst[g];
    const float v = vals[g];
    const float* __restrict__ arow = inp + (size_t)s * IN;
    const float* __restrict__ W = weights + (size_t)r * IN * OUT;
    float a0 = 0.f, a1 = 0.f;
    for (int k = 0; k < IN; ++k) {
        const float av = arow[k];
        a0 = fmaf(av, W[k * OUT + lane], a0);
        a1 = fmaf(av, W[k * OUT + lane + 64], a1);
    }
    float* orow = out + (size_t)d * OUT;
    __hip_atomic_fetch_add(orow + lane, v * a0, __ATOMIC_RELAXED,
                           __HIP_MEMORY_SCOPE_AGENT);
    __hip_atomic_fetch_add(orow + lane + 64, v * a1, __ATOMIC_RELAXED,
                           __HIP_MEMORY_SCOPE_AGENT);
}

extern "C" void kernel_launch(void* const* d_in, const int* in_sizes, int n_in,
                              void* d_out, int out_size, void* d_ws, size_t ws_size,
                              hipStream_t stream) {
    const float* inp     = (const float*)d_in[0];
    const int*   src     = (const int*)  d_in[1];
    const int*   dst     = (const int*)  d_in[2];
    const float* vals    = (const float*)d_in[3];
    const float* weights = (const float*)d_in[4];
    float* out = (float*)d_out;

    const int n_nodes = in_sizes[0] / IN;            // 50000
    const int n_rel   = in_sizes[4] / (IN * OUT);    // 8
    const int n_edges = in_sizes[1] / n_rel;         // 100000

    auto align_up = [](size_t x) { return (x + 255) & ~(size_t)255; };
    const size_t sz_inpb = align_up((size_t)n_nodes * IN * 2);
    const size_t sz_wt   = align_up((size_t)n_rel * IN * OUT * 2);

    const int conv_n8 = n_nodes * IN / 8;
    const int wt_tot  = n_rel * IN * OUT;
    const int gemm_gx = (n_nodes + 127) / 128;
    const int edge_gx = (n_edges + 255) / 256;

    // try: nr relations per pass (nr = n_rel -> single pass)
    for (int nr = n_rel; nr >= 1; nr = (nr == 1) ? 0 : nr / 2) {
        const int S = nr * n_nodes;
        const int nb = (S + 1023) / 1024;
        const size_t sz_counts = align_up((size_t)S * 4);
        const size_t sz_offs   = align_up((size_t)(S + 1) * 4);
        const size_t sz_cursor = align_up((size_t)S * 4);
        const size_t sz_bsum   = align_up((size_t)nb * 4);
        const size_t sz_csr    = align_up((size_t)nr * n_edges * 8);
        const size_t sz_agg    = (size_t)S * IN * 2;
        const size_t need = sz_inpb + sz_wt + sz_counts + sz_offs + sz_cursor
                          + sz_bsum + sz_csr + sz_agg;
        if (need > ws_size) continue;

        char* p = (char*)d_ws;
        unsigned short* inpb = (unsigned short*)p;  p += sz_inpb;
        unsigned short* wtb  = (unsigned short*)p;  p += sz_wt;
        int*  counts = (int*)p;   p += sz_counts;
        int*  offs   = (int*)p;   p += sz_offs;
        int*  cursor = (int*)p;   p += sz_cursor;
        int*  bsum   = (int*)p;   p += sz_bsum;
        int2* csr    = (int2*)p;  p += sz_csr;
        unsigned short* agg = (unsigned short*)p;

        conv_inp_kernel<<<(conv_n8 + 255) / 256, 256, 0, stream>>>(
            inp, inpb, conv_n8);
        conv_w_kernel<<<(wt_tot + 255) / 256, 256, 0, stream>>>(
            weights, wtb, wt_tot);

        for (int rb = 0; rb < n_rel; rb += nr) {
            const int rc = (rb + nr <= n_rel) ? nr : (n_rel - rb);
            const int Sc = rc * n_nodes;
            const int nbc = (Sc + 1023) / 1024;
            const size_t eoff = (size_t)rb * n_edges;

            hipMemsetAsync(counts, 0, (size_t)Sc * 4, stream);
            {
                dim3 g(edge_gx, rc);
                hist_kernel<<<g, 256, 0, stream>>>(dst + eoff, counts,
                                                   n_edges, n_nodes);
            }
            scan_local_kernel<<<nbc, 256, 0, stream>>>(counts, offs, bsum, Sc);
            scan_top_kernel<<<1, 256, 0, stream>>>(bsum, nbc, offs, Sc);
            scan_apply_kernel<<<(Sc + 255) / 256, 256, 0, stream>>>(
                offs, bsum, cursor, Sc);
            {
                dim3 g(edge_gx, rc);
                fill_kernel<<<g, 256, 0, stream>>>(src + eoff, dst + eoff,
                                                   vals + eoff, cursor, csr,
                                                   n_edges, n_nodes);
            }
            gather_agg_kernel<<<(Sc + 7) / 8, 256, 0, stream>>>(
                inpb, csr, offs, agg, Sc);
            mfma_gemm<<<gemm_gx, 256, 0, stream>>>(
                agg, wtb, out, rb, rc, n_nodes, rb > 0 ? 1 : 0);
        }
        return;
    }

    // last resort: no workspace needed
    hipMemsetAsync(out, 0, (size_t)n_nodes * OUT * 4, stream);
    dim3 g((n_edges + 3) / 4, n_rel);
    gemv_scatter_kernel<<<g, 256, 0, stream>>>(inp, weights, src, dst, vals,
                                               out, n_edges);
}

// Round 6
// 249.865 us; speedup vs baseline: 1.1266x; 1.1266x over previous
//
#include <hip/hip_runtime.h>

// GCN layer: out = sum_r segment_sum(vals_r * inp[src_r], dst_r) @ W_r
// Round 6 (fused aggregate+GEMM):
//   1) inp -> bf16 (12.8 MB), W -> Wt[r][n][k] bf16.
//   2) compact CSR keyed by seg=(r*N+dst): hist -> 3-kernel scan -> fill.
//   3) fused kernel: block = 64 dst rows x 128 cols. Per relation: gather
//      agg rows straight into LDS (4 thr/row, f32 regs -> bf16 pack), then
//      MFMA-accumulate all relations in registers; out f32 written once.
//      No h / agg intermediate (saves ~200 MB of HBM/L3 round-trip).
// N=50000, R=8, E=100000, IN=OUT=128.

constexpr int IN    = 128;
constexpr int OUT   = 128;
constexpr int LDK   = 136;   // padded LDS row (bf16) = 272 B
constexpr int BROWS = 64;    // dst rows per block

typedef __attribute__((ext_vector_type(8))) short bf16x8;
typedef __attribute__((ext_vector_type(4))) float f32x4;

__device__ inline unsigned short f2bf(float f) {
    unsigned int u = __float_as_uint(f);
    u += 0x7fffu + ((u >> 16) & 1u);          // RNE
    return (unsigned short)(u >> 16);
}
__device__ inline float bflo(unsigned int u) { return __uint_as_float(u << 16); }
__device__ inline float bfhi(unsigned int u) { return __uint_as_float(u & 0xffff0000u); }

// ---------------- converts --------------------------------------------------
__global__ __launch_bounds__(256) void conv_inp_kernel(
    const float* __restrict__ x, unsigned short* __restrict__ y, int n8)
{
    const int i = blockIdx.x * 256 + threadIdx.x;
    if (i >= n8) return;
    const float4 a = ((const float4*)x)[i * 2];
    const float4 b = ((const float4*)x)[i * 2 + 1];
    uint4 o;
    o.x = (unsigned)f2bf(a.x) | ((unsigned)f2bf(a.y) << 16);
    o.y = (unsigned)f2bf(a.z) | ((unsigned)f2bf(a.w) << 16);
    o.z = (unsigned)f2bf(b.x) | ((unsigned)f2bf(b.y) << 16);
    o.w = (unsigned)f2bf(b.z) | ((unsigned)f2bf(b.w) << 16);
    ((uint4*)y)[i] = o;
}

// Wt[r][n][k] = W[r][k][n], bf16
__global__ __launch_bounds__(256) void conv_w_kernel(
    const float* __restrict__ w, unsigned short* __restrict__ wt, int total)
{
    const int t = blockIdx.x * 256 + threadIdx.x;
    if (t >= total) return;
    const int r = t >> 14, rem = t & 16383;
    const int n = rem >> 7, k = rem & 127;
    wt[t] = f2bf(w[(r << 14) + (k << 7) + n]);
}

// ---------------- CSR build: hist + hierarchical scan + fill ----------------
__global__ __launch_bounds__(256) void hist_kernel(
    const int* __restrict__ dst, int* __restrict__ counts,
    int n_edges, int n_nodes)
{
    const int e = blockIdx.x * 256 + threadIdx.x;
    if (e >= n_edges) return;
    const size_t g = (size_t)blockIdx.y * n_edges + e;
    atomicAdd(&counts[blockIdx.y * n_nodes + dst[g]], 1);
}

__global__ __launch_bounds__(256) void scan_local_kernel(
    const int* __restrict__ counts, int* __restrict__ offs,
    int* __restrict__ blocksum, int S)
{
    __shared__ int ps[256];
    const int tid = threadIdx.x;
    const int base = blockIdx.x * 1024 + tid * 4;
    int c[4];
    #pragma unroll
    for (int i = 0; i < 4; ++i) c[i] = (base + i < S) ? counts[base + i] : 0;
    const int total = c[0] + c[1] + c[2] + c[3];
    ps[tid] = total;
    __syncthreads();
    #pragma unroll
    for (int d = 1; d < 256; d <<= 1) {
        const int v = (tid >= d) ? ps[tid - d] : 0;
        __syncthreads();
        ps[tid] += v;
        __syncthreads();
    }
    int run = ps[tid] - total;
    #pragma unroll
    for (int i = 0; i < 4; ++i) {
        if (base + i < S) offs[base + i] = run;
        run += c[i];
    }
    if (tid == 255) blocksum[blockIdx.x] = ps[255];
}

__global__ __launch_bounds__(256) void scan_top_kernel(
    int* __restrict__ blocksum, int nb, int* __restrict__ offs, int S)
{
    __shared__ int ps[256];
    const int tid = threadIdx.x;
    const int chunk = (nb + 255) / 256;
    const int lo = tid * chunk;
    const int hi = (lo + chunk < nb) ? lo + chunk : nb;
    int vals[8];
    int s = 0;
    for (int i = lo; i < hi; ++i) { vals[i - lo] = blocksum[i]; s += vals[i - lo]; }
    ps[tid] = s;
    __syncthreads();
    #pragma unroll
    for (int d = 1; d < 256; d <<= 1) {
        const int v = (tid >= d) ? ps[tid - d] : 0;
        __syncthreads();
        ps[tid] += v;
        __syncthreads();
    }
    int run = ps[tid] - s;
    for (int i = lo; i < hi; ++i) { const int v = vals[i - lo]; blocksum[i] = run; run += v; }
    if (tid == 255) offs[S] = ps[255];
}

__global__ __launch_bounds__(256) void scan_apply_kernel(
    int* __restrict__ offs, const int* __restrict__ blocksum,
    int* __restrict__ cursor, int S)
{
    const int i = blockIdx.x * 256 + threadIdx.x;
    if (i >= S) return;
    const int v = offs[i] + blocksum[i >> 10];
    offs[i] = v;
    cursor[i] = v;
}

__global__ __launch_bounds__(256) void fill_kernel(
    const int* __restrict__ src, const int* __restrict__ dst,
    const float* __restrict__ vals, int* __restrict__ cursor,
    int2* __restrict__ csr, int n_edges, int n_nodes)
{
    const int e = blockIdx.x * 256 + threadIdx.x;
    if (e >= n_edges) return;
    const size_t g = (size_t)blockIdx.y * n_edges + e;
    const int seg = blockIdx.y * n_nodes + dst[g];
    const int pos = atomicAdd(&cursor[seg], 1);
    csr[pos] = make_int2(src[g], __float_as_int(vals[g]));
}

// ---------------- fused aggregate + GEMM ------------------------------------
// Block: 64 dst rows x 128 out cols, 256 thr = 4 waves. Loop over relations:
//   stage: thread (row=t>>2, qt=t&3) gathers sum val*inpb[src][qt*32..+31]
//          into 32 f32 regs from the CSR run of seg=(r*N+row), packs bf16
//          into As[row][qt*32..]. Divergent edge loop costs VALU only
//          (exec-masked lanes issue no loads).
//   mfma:  wave w = cols w*32..+31 (2 N-tiles), 4 M-tiles, K=128 -> 32 MFMAs
//          per relation; acc registers persist across relations.
// Store: out f32 written once (accum adds for multi-pass fallback).
__global__ __launch_bounds__(256) void fused_agg_gemm(
    const unsigned short* __restrict__ inpb,
    const unsigned short* __restrict__ wt,
    const int2* __restrict__ csr, const int* __restrict__ offs,
    float* __restrict__ out, int rel_base, int rel_count,
    int n_nodes, int accum)
{
    __shared__ unsigned short As[BROWS * LDK];   // 17.4 KB

    const int row0 = blockIdx.x * BROWS;
    const int tid  = threadIdx.x;
    const int wave = tid >> 6, lane = tid & 63;
    const int m = lane & 15, q = lane >> 4;
    const int srow = tid >> 2;      // staging row 0..63
    const int qt   = tid & 3;       // col quarter

    f32x4 acc[4][2];
    #pragma unroll
    for (int mt = 0; mt < 4; ++mt)
        #pragma unroll
        for (int nt = 0; nt < 2; ++nt)
            acc[mt][nt] = (f32x4){0.f, 0.f, 0.f, 0.f};

    for (int r = 0; r < rel_count; ++r) {
        __syncthreads();   // protect As from previous iteration's readers

        // ---- stage agg rows into LDS ----
        float accs[32];
        #pragma unroll
        for (int i = 0; i < 32; ++i) accs[i] = 0.f;
        const int grow = row0 + srow;
        if (grow < n_nodes) {
            const int seg = r * n_nodes + grow;
            const int b = offs[seg], e = offs[seg + 1];
            for (int j = b; j < e; ++j) {
                const int2 rec = csr[j];
                const float v = __int_as_float(rec.y);
                const uint4* gp =
                    (const uint4*)(inpb + (size_t)rec.x * IN + qt * 32);
                #pragma unroll
                for (int w4 = 0; w4 < 4; ++w4) {
                    const uint4 u = gp[w4];
                    accs[w4*8+0] += v * bflo(u.x);
                    accs[w4*8+1] += v * bfhi(u.x);
                    accs[w4*8+2] += v * bflo(u.y);
                    accs[w4*8+3] += v * bfhi(u.y);
                    accs[w4*8+4] += v * bflo(u.z);
                    accs[w4*8+5] += v * bfhi(u.z);
                    accs[w4*8+6] += v * bflo(u.w);
                    accs[w4*8+7] += v * bfhi(u.w);
                }
            }
        }
        {
            unsigned int* lp = (unsigned int*)&As[srow * LDK + qt * 32];
            #pragma unroll
            for (int i = 0; i < 16; ++i)
                lp[i] = (unsigned)f2bf(accs[2*i])
                      | ((unsigned)f2bf(accs[2*i+1]) << 16);
        }

        // ---- B fragments for this relation (L2-hot wt) ----
        bf16x8 bfrag[2][4];
        {
            const unsigned short* wtr =
                wt + ((size_t)(rel_base + r) * OUT + wave * 32) * IN;
            #pragma unroll
            for (int nt = 0; nt < 2; ++nt)
                #pragma unroll
                for (int ks = 0; ks < 4; ++ks)
                    bfrag[nt][ks] = *(const bf16x8*)(
                        wtr + (size_t)(nt * 16 + m) * IN + ks * 32 + q * 8);
        }
        __syncthreads();

        // ---- MFMA ----
        #pragma unroll
        for (int ks = 0; ks < 4; ++ks) {
            bf16x8 a[4];
            #pragma unroll
            for (int mt = 0; mt < 4; ++mt)
                a[mt] = *(const bf16x8*)&As[(mt*16 + m) * LDK + ks*32 + q*8];
            #pragma unroll
            for (int mt = 0; mt < 4; ++mt) {
                acc[mt][0] = __builtin_amdgcn_mfma_f32_16x16x32_bf16(
                    a[mt], bfrag[0][ks], acc[mt][0], 0, 0, 0);
                acc[mt][1] = __builtin_amdgcn_mfma_f32_16x16x32_bf16(
                    a[mt], bfrag[1][ks], acc[mt][1], 0, 0, 0);
            }
        }
    }

    // ---- store: C/D lane holds rows q*4+0..3, col = nt*16 + m ----
    #pragma unroll
    for (int mt = 0; mt < 4; ++mt) {
        #pragma unroll
        for (int rg = 0; rg < 4; ++rg) {
            const int row = row0 + mt * 16 + q * 4 + rg;
            if (row < n_nodes) {
                float* op = out + (size_t)row * OUT + wave * 32 + m;
                float v0 = acc[mt][0][rg], v1 = acc[mt][1][rg];
                if (accum) { v0 += op[0]; v1 += op[16]; }
                op[0] = v0; op[16] = v1;
            }
        }
    }
}

// ---------------- last resort: per-edge GEMV scatter (no workspace) ---------
__global__ __launch_bounds__(256) void gemv_scatter_kernel(
    const float* __restrict__ inp, const float* __restrict__ weights,
    const int* __restrict__ src, const int* __restrict__ dst,
    const float* __restrict__ vals, float* __restrict__ out, int n_edges)
{
    const int e = blockIdx.x * 4 + (threadIdx.x >> 6);
    if (e >= n_edges) return;
    const int lane = threadIdx.x & 63;
    const int r = blockIdx.y;
    const size_t g = (size_t)r * n_edges + e;
    const int s = src[g], d = dst[g];
    const float v = vals[g];
    const float* __restrict__ arow = inp + (size_t)s * IN;
    const float* __restrict__ W = weights + (size_t)r * IN * OUT;
    float a0 = 0.f, a1 = 0.f;
    for (int k = 0; k < IN; ++k) {
        const float av = arow[k];
        a0 = fmaf(av, W[k * OUT + lane], a0);
        a1 = fmaf(av, W[k * OUT + lane + 64], a1);
    }
    float* orow = out + (size_t)d * OUT;
    __hip_atomic_fetch_add(orow + lane, v * a0, __ATOMIC_RELAXED,
                           __HIP_MEMORY_SCOPE_AGENT);
    __hip_atomic_fetch_add(orow + lane + 64, v * a1, __ATOMIC_RELAXED,
                           __HIP_MEMORY_SCOPE_AGENT);
}

extern "C" void kernel_launch(void* const* d_in, const int* in_sizes, int n_in,
                              void* d_out, int out_size, void* d_ws, size_t ws_size,
                              hipStream_t stream) {
    const float* inp     = (const float*)d_in[0];
    const int*   src     = (const int*)  d_in[1];
    const int*   dst     = (const int*)  d_in[2];
    const float* vals    = (const float*)d_in[3];
    const float* weights = (const float*)d_in[4];
    float* out = (float*)d_out;

    const int n_nodes = in_sizes[0] / IN;            // 50000
    const int n_rel   = in_sizes[4] / (IN * OUT);    // 8
    const int n_edges = in_sizes[1] / n_rel;         // 100000

    auto align_up = [](size_t x) { return (x + 255) & ~(size_t)255; };
    const size_t sz_inpb = align_up((size_t)n_nodes * IN * 2);
    const size_t sz_wt   = align_up((size_t)n_rel * IN * OUT * 2);

    const int conv_n8 = n_nodes * IN / 8;
    const int wt_tot  = n_rel * IN * OUT;
    const int fuse_gx = (n_nodes + BROWS - 1) / BROWS;
    const int edge_gx = (n_edges + 255) / 256;

    // nr relations per pass (nr = n_rel -> single pass, no agg/h anywhere)
    for (int nr = n_rel; nr >= 1; nr = (nr == 1) ? 0 : nr / 2) {
        const int S = nr * n_nodes;
        const int nb = (S + 1023) / 1024;
        const size_t sz_counts = align_up((size_t)S * 4);
        const size_t sz_offs   = align_up((size_t)(S + 1) * 4);
        const size_t sz_cursor = align_up((size_t)S * 4);
        const size_t sz_bsum   = align_up((size_t)nb * 4);
        const size_t sz_csr    = align_up((size_t)nr * n_edges * 8);
        const size_t need = sz_inpb + sz_wt + sz_counts + sz_offs + sz_cursor
                          + sz_bsum + sz_csr;
        if (need > ws_size) continue;

        char* p = (char*)d_ws;
        unsigned short* inpb = (unsigned short*)p;  p += sz_inpb;
        unsigned short* wtb  = (unsigned short*)p;  p += sz_wt;
        int*  counts = (int*)p;   p += sz_counts;
        int*  offs   = (int*)p;   p += sz_offs;
        int*  cursor = (int*)p;   p += sz_cursor;
        int*  bsum   = (int*)p;   p += sz_bsum;
        int2* csr    = (int2*)p;

        conv_inp_kernel<<<(conv_n8 + 255) / 256, 256, 0, stream>>>(
            inp, inpb, conv_n8);
        conv_w_kernel<<<(wt_tot + 255) / 256, 256, 0, stream>>>(
            weights, wtb, wt_tot);

        for (int rb = 0; rb < n_rel; rb += nr) {
            const int rc = (rb + nr <= n_rel) ? nr : (n_rel - rb);
            const int Sc = rc * n_nodes;
            const int nbc = (Sc + 1023) / 1024;
            const size_t eoff = (size_t)rb * n_edges;

            hipMemsetAsync(counts, 0, (size_t)Sc * 4, stream);
            {
                dim3 g(edge_gx, rc);
                hist_kernel<<<g, 256, 0, stream>>>(dst + eoff, counts,
                                                   n_edges, n_nodes);
            }
            scan_local_kernel<<<nbc, 256, 0, stream>>>(counts, offs, bsum, Sc);
            scan_top_kernel<<<1, 256, 0, stream>>>(bsum, nbc, offs, Sc);
            scan_apply_kernel<<<(Sc + 255) / 256, 256, 0, stream>>>(
                offs, bsum, cursor, Sc);
            {
                dim3 g(edge_gx, rc);
                fill_kernel<<<g, 256, 0, stream>>>(src + eoff, dst + eoff,
                                                   vals + eoff, cursor, csr,
                                                   n_edges, n_nodes);
            }
            fused_agg_gemm<<<fuse_gx, 256, 0, stream>>>(
                inpb, wtb, csr, offs, out, rb, rc, n_nodes, rb > 0 ? 1 : 0);
        }
        return;
    }

    // last resort: no workspace needed
    hipMemsetAsync(out, 0, (size_t)n_nodes * OUT * 4, stream);
    dim3 g((n_edges + 3) / 4, n_rel);
    gemv_scatter_kernel<<<g, 256, 0, stream>>>(inp, weights, src, dst, vals,
                                               out, n_edges);
}